// Round 15
// baseline (169.147 us; speedup 1.0000x reference)
//
#include <hip/hip_runtime.h>
#include <math.h>

#define CCH   256
#define NPIX  4096
#define BATCH 4

typedef __attribute__((ext_vector_type(8)))  short    s16x8;
typedef __attribute__((ext_vector_type(4)))  short    s16x4;
typedef __attribute__((ext_vector_type(8)))  _Float16 f16x8;
typedef __attribute__((ext_vector_type(4)))  float    f32x4;
typedef __attribute__((ext_vector_type(16))) float    f32x16;

union U8 { unsigned int u[4]; s16x8 v; };

__device__ __forceinline__ unsigned short f2bf(float f) {
    unsigned int u = __float_as_uint(f);
    u += 0x7fff + ((u >> 16) & 1);          // RNE; values are finite
    return (unsigned short)(u >> 16);
}
__device__ __forceinline__ float bf2f(unsigned short h) {
    return __uint_as_float(((unsigned int)h) << 16);
}
__device__ __forceinline__ unsigned short f2h(float f) {
    _Float16 h = (_Float16)f;               // v_cvt_f16_f32, RNE
    return *(unsigned short*)&h;
}
__device__ __forceinline__ float h2f(unsigned short u) {
    _Float16 h = *(_Float16*)&u;
    return (float)h;
}
__device__ __forceinline__ unsigned int cvtpk_bf16(float lo, float hi) {
    unsigned int r;
    asm("v_cvt_pk_bf16_f32 %0, %1, %2" : "=v"(r) : "v"(lo), "v"(hi));
    return r;
}

// ---- 32x32x16 fragment addressing ----
// q/k frag, value X[pixel n][dim d]:
//   tile=n>>5, frag kh=d>>4, lane=((d>>3)&1)*32+(n&31), elem=d&7
// (A-operand: rows=pixel(j), B-operand: cols=pixel(i) -- same storage serves both.)
__device__ __forceinline__ size_t qk_addr32(int b, int n, int d) {
    return (((((size_t)b * 128 + (n >> 5)) * 2 + (d >> 4)) * 64
             + (((d >> 3) & 1) << 5) + (n & 31)) << 3) + (d & 7);
}
// V A-frag for PV (A = V[32c x 16j]):
//   jt=j>>5, ct=c>>5, kh=(j>>4)&1, lane=((j>>3)&1)*32+(c&31), elem=j&7
__device__ __forceinline__ size_t v_addr32(int b, int j, int c) {
    return ((((((size_t)b * 128 + (j >> 5)) * 8 + (c >> 5)) * 2 + ((j >> 4) & 1)) * 64
             + (((j >> 3) & 1) << 5) + (c & 31)) << 3) + (j & 7);
}

// ---------------- W -> A-frag fp16 (hi/lo for q,k; hi for v), once ----------------
// (unchanged -- W frag layout is internal to proj's 16x16 MFMAs)
__global__ __launch_bounds__(64) void wcast_kernel(
    const float* __restrict__ Wq, const float* __restrict__ bq,
    const float* __restrict__ Wk, const float* __restrict__ bk,
    const float* __restrict__ Wv, const float* __restrict__ bv,
    unsigned short* __restrict__ wfh, unsigned short* __restrict__ wfl,
    float* __restrict__ bias_ws)
{
    const int rt = blockIdx.x;
    const int lane = threadIdx.x, l15 = lane & 15, quad = lane >> 4;
    const float *Ws, *bs; int roff; float scale = 1.0f;
    if (rt < 2)      { Ws = Wq; bs = bq; roff = rt * 16;      scale = 1.44269504f; }
    else if (rt < 4) { Ws = Wk; bs = bk; roff = (rt - 2) * 16; }
    else             { Ws = Wv; bs = bv; roff = (rt - 4) * 16; }

    const float* wrow = Ws + (size_t)(roff + l15) * CCH + quad * 8;
    for (int kb = 0; kb < 8; ++kb) {
        s16x8 h, l;
        #pragma unroll
        for (int d = 0; d < 8; ++d) {
            float wv = wrow[kb * 32 + d] * scale;
            unsigned short hh = f2h(wv);
            h[d] = (short)hh;
            l[d] = (short)f2h(wv - h2f(hh));
        }
        *(s16x8*)&wfh[(((size_t)rt * 8 + kb) * 64 + lane) * 8] = h;
        if (rt < 4) *(s16x8*)&wfl[(((size_t)rt * 8 + kb) * 64 + lane) * 8] = l;
    }
    if (lane < 16) bias_ws[rt * 16 + lane] = bs[roff + lane] * scale;
}

// ---------------- fused cast+projection (R12-verified math; NEW output layouts) ----------------
__global__ __launch_bounds__(256, 4) void proj_kernel(
    const float* __restrict__ x,
    const unsigned short* __restrict__ wfh, const unsigned short* __restrict__ wfl,
    const float* __restrict__ bias_ws,
    unsigned short* __restrict__ q_hi, unsigned short* __restrict__ k_hi,
    unsigned short* __restrict__ v_frag)
{
    __shared__ float xs[16][260];   // [col 0..15][row 0..255], +4 pad

    const int t = threadIdx.x;
    const int rh = t >> 6, lane = t & 63, l15 = lane & 15, quad = lane >> 4;
    const int b = blockIdx.y;
    const int nt = blockIdx.x;

    {
        const float* xrow = x + (size_t)b * CCH * NPIX + nt * 16;
        #pragma unroll
        for (int i = 0; i < 4; ++i) {
            const int r  = i * 64 + (t >> 2);
            const int c4 = (t & 3) * 4;
            const float4 v = *(const float4*)&xrow[(size_t)r * NPIX + c4];
            xs[c4 + 0][r] = v.x;
            xs[c4 + 1][r] = v.y;
            xs[c4 + 2][r] = v.z;
            xs[c4 + 3][r] = v.w;
        }
    }
    __syncthreads();

    f32x4 aq0 = {0.f, 0.f, 0.f, 0.f};
    f32x4 aq1 = {0.f, 0.f, 0.f, 0.f};
    f32x4 av[4];
    #pragma unroll
    for (int i = 0; i < 4; ++i) av[i] = (f32x4){0.f, 0.f, 0.f, 0.f};

    #pragma unroll 2
    for (int kb = 0; kb < 8; ++kb) {
        const float4 xv0 = *(const float4*)&xs[l15][kb * 32 + quad * 8];
        const float4 xv1 = *(const float4*)&xs[l15][kb * 32 + quad * 8 + 4];
        const float xa[8] = { xv0.x, xv0.y, xv0.z, xv0.w,
                              xv1.x, xv1.y, xv1.z, xv1.w };
        f16x8 xh, xl;
        #pragma unroll
        for (int d = 0; d < 8; ++d) {
            const float xv = xa[d];
            _Float16 hh = (_Float16)xv;
            xh[d] = hh;
            xl[d] = (_Float16)(xv - (float)hh);
        }
        {
            const f16x8 ah = *(const f16x8*)&wfh[(((size_t)rh * 8 + kb) * 64 + lane) * 8];
            const f16x8 al = *(const f16x8*)&wfl[(((size_t)rh * 8 + kb) * 64 + lane) * 8];
            aq0 = __builtin_amdgcn_mfma_f32_16x16x32_f16(ah, xh, aq0, 0, 0, 0);
            aq1 = __builtin_amdgcn_mfma_f32_16x16x32_f16(ah, xl, aq1, 0, 0, 0);
            aq1 = __builtin_amdgcn_mfma_f32_16x16x32_f16(al, xh, aq1, 0, 0, 0);
        }
        #pragma unroll
        for (int i = 0; i < 4; ++i) {
            const int rt = 4 + rh * 4 + i;
            const f16x8 ah = *(const f16x8*)&wfh[(((size_t)rt * 8 + kb) * 64 + lane) * 8];
            av[i] = __builtin_amdgcn_mfma_f32_16x16x32_f16(ah, xh, av[i], 0, 0, 0);
        }
    }

    const int n = nt * 16 + l15;
    // q/k: single fp16 into 32x32-frag order; 4 consecutive elems -> s16x4
    {
        s16x4 h4;
        #pragma unroll
        for (int rr = 0; rr < 4; ++rr) {
            const int rloc = quad * 4 + rr;
            const float val = aq0[rr] + aq1[rr] + bias_ws[rh * 16 + rloc];
            h4[rr] = (short)f2h(val);
        }
        const int d0 = (rh & 1) * 16 + quad * 4;     // d0..d0+3 share (d>>3) group
        const size_t a = qk_addr32(b, n, d0);
        if (rh < 2) *(s16x4*)&q_hi[a] = h4;
        else        *(s16x4*)&k_hi[a] = h4;
    }
    // v: bf16 into 32x32 A-frag order
    #pragma unroll
    for (int i = 0; i < 4; ++i) {
        const int vt = rh * 4 + i;
        #pragma unroll
        for (int rr = 0; rr < 4; ++rr) {
            const int rloc = quad * 4 + rr;
            const float val = av[i][rr] + bias_ws[(4 + vt) * 16 + rloc];
            v_frag[v_addr32(b, n, vt * 16 + rloc)] = f2bf(val);
        }
    }
}

// ---------------- flash attention: 32x32 swapped-QK, BARRIER-FREE main loop ----------------
// 512 blocks x 512 threads (8 waves).  Block = (b, ib: 32-pixel i-tile).
// Wave (cg = w&1: c-half of 128, jg = w>>1: j-quarter of 32 j-tiles).
// Per j-tile (32 j): S = mfma32x32x16_f16(K, Q) x2  ->  S[j][i] in-register
// (col=lane&31=i, row=(r&3)+8(r>>2)+4(lane>>5)=j).  exp2 in-register; repack
// to PV B-frags via cvt_pk_bf16 + shfl_xor(32) + select (lane-half exchange).
// PV: 8x mfma32x32x16_bf16(V, P) into 4 c-tile accumulators.  Denominator via
// ones-MFMA (matrix pipe has slack -- R13).  QK duplicated across cg (+12.5%).
// NO barriers in the loop; 3 __syncthreads in the epilogue tree-reduce.
#define TILE32(JT, KC0, KC1, KN0, KN1, DO_PF) do { \
    const int jt_ = (JT); \
    const size_t vb_ = (((size_t)b * 128 + jt_) * 8 + cg * 4) * 1024 + (size_t)lane * 8; \
    const s16x8 Vf0 = *(const s16x8*)(v_frag + vb_); \
    const s16x8 Vf1 = *(const s16x8*)(v_frag + vb_ + 512); \
    const s16x8 Vf2 = *(const s16x8*)(v_frag + vb_ + 1024); \
    const s16x8 Vf3 = *(const s16x8*)(v_frag + vb_ + 1536); \
    const s16x8 Vf4 = *(const s16x8*)(v_frag + vb_ + 2048); \
    const s16x8 Vf5 = *(const s16x8*)(v_frag + vb_ + 2560); \
    const s16x8 Vf6 = *(const s16x8*)(v_frag + vb_ + 3072); \
    const s16x8 Vf7 = *(const s16x8*)(v_frag + vb_ + 3584); \
    f32x16 S = __builtin_amdgcn_mfma_f32_32x32x16_f16((KC0), Q0, \
        (f32x16){0,0,0,0,0,0,0,0,0,0,0,0,0,0,0,0}, 0, 0, 0); \
    S = __builtin_amdgcn_mfma_f32_32x32x16_f16((KC1), Q1, S, 0, 0, 0); \
    if (DO_PF) { \
        const size_t kb_ = ((size_t)(b * 128 + jt_ + 1) * 2) * 512 + (size_t)lane * 8; \
        KN0 = *(const f16x8*)(k_hi + kb_); \
        KN1 = *(const f16x8*)(k_hi + kb_ + 512); \
    } \
    const unsigned int pk0 = cvtpk_bf16(__builtin_exp2f(S[0]),  __builtin_exp2f(S[1])); \
    const unsigned int pk1 = cvtpk_bf16(__builtin_exp2f(S[2]),  __builtin_exp2f(S[3])); \
    const unsigned int pk2 = cvtpk_bf16(__builtin_exp2f(S[4]),  __builtin_exp2f(S[5])); \
    const unsigned int pk3 = cvtpk_bf16(__builtin_exp2f(S[6]),  __builtin_exp2f(S[7])); \
    const unsigned int pk4 = cvtpk_bf16(__builtin_exp2f(S[8]),  __builtin_exp2f(S[9])); \
    const unsigned int pk5 = cvtpk_bf16(__builtin_exp2f(S[10]), __builtin_exp2f(S[11])); \
    const unsigned int pk6 = cvtpk_bf16(__builtin_exp2f(S[12]), __builtin_exp2f(S[13])); \
    const unsigned int pk7 = cvtpk_bf16(__builtin_exp2f(S[14]), __builtin_exp2f(S[15])); \
    const unsigned int sx0 = (unsigned int)__shfl_xor((int)pk0, 32, 64); \
    const unsigned int sx1 = (unsigned int)__shfl_xor((int)pk1, 32, 64); \
    const unsigned int sx2 = (unsigned int)__shfl_xor((int)pk2, 32, 64); \
    const unsigned int sx3 = (unsigned int)__shfl_xor((int)pk3, 32, 64); \
    const unsigned int sx4 = (unsigned int)__shfl_xor((int)pk4, 32, 64); \
    const unsigned int sx5 = (unsigned int)__shfl_xor((int)pk5, 32, 64); \
    const unsigned int sx6 = (unsigned int)__shfl_xor((int)pk6, 32, 64); \
    const unsigned int sx7 = (unsigned int)__shfl_xor((int)pk7, 32, 64); \
    U8 b0_, b1_; \
    b0_.u[0] = lo_half ? pk0 : sx2;  b0_.u[1] = lo_half ? pk1 : sx3; \
    b0_.u[2] = lo_half ? sx0 : pk2;  b0_.u[3] = lo_half ? sx1 : pk3; \
    b1_.u[0] = lo_half ? pk4 : sx6;  b1_.u[1] = lo_half ? pk5 : sx7; \
    b1_.u[2] = lo_half ? sx4 : pk6;  b1_.u[3] = lo_half ? sx5 : pk7; \
    const s16x8 B0 = b0_.v, B1 = b1_.v; \
    dacc = __builtin_amdgcn_mfma_f32_32x32x16_bf16(onesA, B0, dacc, 0, 0, 0); \
    dacc = __builtin_amdgcn_mfma_f32_32x32x16_bf16(onesA, B1, dacc, 0, 0, 0); \
    acc0 = __builtin_amdgcn_mfma_f32_32x32x16_bf16(Vf0, B0, acc0, 0, 0, 0); \
    acc0 = __builtin_amdgcn_mfma_f32_32x32x16_bf16(Vf1, B1, acc0, 0, 0, 0); \
    acc1 = __builtin_amdgcn_mfma_f32_32x32x16_bf16(Vf2, B0, acc1, 0, 0, 0); \
    acc1 = __builtin_amdgcn_mfma_f32_32x32x16_bf16(Vf3, B1, acc1, 0, 0, 0); \
    acc2 = __builtin_amdgcn_mfma_f32_32x32x16_bf16(Vf4, B0, acc2, 0, 0, 0); \
    acc2 = __builtin_amdgcn_mfma_f32_32x32x16_bf16(Vf5, B1, acc2, 0, 0, 0); \
    acc3 = __builtin_amdgcn_mfma_f32_32x32x16_bf16(Vf6, B0, acc3, 0, 0, 0); \
    acc3 = __builtin_amdgcn_mfma_f32_32x32x16_bf16(Vf7, B1, acc3, 0, 0, 0); \
} while (0)

__global__ __launch_bounds__(512, 2) void attn_kernel(
    const unsigned short* __restrict__ q_hi,
    const unsigned short* __restrict__ k_hi,
    const unsigned short* __restrict__ v_frag,
    const float* __restrict__ x, float* __restrict__ out)
{
    __shared__ float comb[4][4][16][64];   // 64 KB (epilogue only)
    __shared__ float dl[4][32];

    const int t = threadIdx.x;
    const int w = t >> 6, lane = t & 63;
    const int cg = w & 1, jg = w >> 1;
    const bool lo_half = (lane < 32);

    const int f = blockIdx.x;                 // 0..511; XCD-pair per batch
    const int xcd = f & 7;
    const int b = xcd >> 1;
    const int ib = ((xcd & 1) << 6) + (f >> 3);   // i-tile 0..127 (32 pixels)

    // Q B-frags (kh 0,1)
    const size_t qb = ((size_t)(b * 128 + ib) * 2) * 512 + (size_t)lane * 8;
    const f16x8 Q0 = *(const f16x8*)(q_hi + qb);
    const f16x8 Q1 = *(const f16x8*)(q_hi + qb + 512);

    const s16x8 onesA = { (short)0x3F80, (short)0x3F80, (short)0x3F80, (short)0x3F80,
                          (short)0x3F80, (short)0x3F80, (short)0x3F80, (short)0x3F80 };

    f32x16 acc0 = {0,0,0,0,0,0,0,0,0,0,0,0,0,0,0,0};
    f32x16 acc1 = {0,0,0,0,0,0,0,0,0,0,0,0,0,0,0,0};
    f32x16 acc2 = {0,0,0,0,0,0,0,0,0,0,0,0,0,0,0,0};
    f32x16 acc3 = {0,0,0,0,0,0,0,0,0,0,0,0,0,0,0,0};
    f32x16 dacc = {0,0,0,0,0,0,0,0,0,0,0,0,0,0,0,0};

    // K double-buffer
    f16x8 kc0, kc1, kn0, kn1;
    const int jt0 = jg * 32;
    {
        const size_t kb0 = ((size_t)(b * 128 + jt0) * 2) * 512 + (size_t)lane * 8;
        kc0 = *(const f16x8*)(k_hi + kb0);
        kc1 = *(const f16x8*)(k_hi + kb0 + 512);
    }
    kn0 = kc0; kn1 = kc1;

    #pragma unroll 1
    for (int s2 = 0; s2 < 16; ++s2) {
        TILE32(jt0 + 2 * s2,     kc0, kc1, kn0, kn1, 1);
        TILE32(jt0 + 2 * s2 + 1, kn0, kn1, kc0, kc1, (s2 < 15));
    }

    // ---- epilogue: tree-reduce acc over jg; dacc via dl ----
    if (cg == 0 && lane < 32) dl[jg][lane] = dacc[0];   // all D rows equal
    if (jg & 1) {
        const int slot = cg * 2 + (jg >> 1);
        #pragma unroll
        for (int r = 0; r < 16; ++r) {
            comb[slot][0][r][lane] = acc0[r];
            comb[slot][1][r][lane] = acc1[r];
            comb[slot][2][r][lane] = acc2[r];
            comb[slot][3][r][lane] = acc3[r];
        }
    }
    __syncthreads();
    if (!(jg & 1)) {
        const int slot = cg * 2 + (jg >> 1);
        #pragma unroll
        for (int r = 0; r < 16; ++r) {
            acc0[r] += comb[slot][0][r][lane];
            acc1[r] += comb[slot][1][r][lane];
            acc2[r] += comb[slot][2][r][lane];
            acc3[r] += comb[slot][3][r][lane];
        }
    }
    __syncthreads();
    if (jg == 2) {
        #pragma unroll
        for (int r = 0; r < 16; ++r) {
            comb[cg * 2][0][r][lane] = acc0[r];
            comb[cg * 2][1][r][lane] = acc1[r];
            comb[cg * 2][2][r][lane] = acc2[r];
            comb[cg * 2][3][r][lane] = acc3[r];
        }
    }
    __syncthreads();
    if (jg == 0) {
        #pragma unroll
        for (int r = 0; r < 16; ++r) {
            acc0[r] += comb[cg * 2][0][r][lane];
            acc1[r] += comb[cg * 2][1][r][lane];
            acc2[r] += comb[cg * 2][2][r][lane];
            acc3[r] += comb[cg * 2][3][r][lane];
        }
        const int l31 = lane & 31;
        const float linv = 1.f / (dl[0][l31] + dl[1][l31] + dl[2][l31] + dl[3][l31]);
        const int ipix = ib * 32 + l31;
        const int rplus = (lane >> 5) << 2;   // +4 c-row for hi lane-half
        const size_t obase = ((size_t)b * CCH + cg * 128) * NPIX + ipix;
        #pragma unroll
        for (int r = 0; r < 16; ++r) {
            const int crow = (r & 3) + ((r >> 2) << 3) + rplus;
            const size_t i0 = obase + (size_t)(crow +  0) * NPIX;
            const size_t i1 = obase + (size_t)(crow + 32) * NPIX;
            const size_t i2 = obase + (size_t)(crow + 64) * NPIX;
            const size_t i3 = obase + (size_t)(crow + 96) * NPIX;
            out[i0] = acc0[r] * linv + x[i0];
            out[i1] = acc1[r] * linv + x[i1];
            out[i2] = acc2[r] * linv + x[i2];
            out[i3] = acc3[r] * linv + x[i3];
        }
    }
}

extern "C" void kernel_launch(void* const* d_in, const int* in_sizes, int n_in,
                              void* d_out, int out_size, void* d_ws, size_t ws_size,
                              hipStream_t stream) {
    const float* x  = (const float*)d_in[0];
    const float* Wq = (const float*)d_in[1];
    const float* bq = (const float*)d_in[2];
    const float* Wk = (const float*)d_in[3];
    const float* bk = (const float*)d_in[4];
    const float* Wv = (const float*)d_in[5];
    const float* bv = (const float*)d_in[6];
    float* out = (float*)d_out;

    unsigned short* ws = (unsigned short*)d_ws;
    unsigned short* q_hi   = ws;                 //   524,288 (fp16, 32x32 frags)
    unsigned short* k_hi   = ws + 1048576;       //   524,288 (fp16, 32x32 frags)
    unsigned short* v_frag = ws + 2097152;       // 4,194,304 (bf16, 32x32 A-frags)
    unsigned short* wfh    = ws + 6291456;       //    81,920 (fp16)
    unsigned short* wfl    = ws + 6373376;       //    16,384 (fp16)
    float*          bias_ws = (float*)(ws + 6389760);  // 320 floats

    wcast_kernel<<<20, 64, 0, stream>>>(Wq, bq, Wk, bk, Wv, bv, wfh, wfl, bias_ws);
    proj_kernel<<<dim3(256, BATCH), 256, 0, stream>>>(x, wfh, wfl, bias_ws,
                                                      q_hi, k_hi, v_frag);
    attn_kernel<<<512, 512, 0, stream>>>(q_hi, k_hi, v_frag, x, out);
}

// Round 16
// 145.831 us; speedup vs baseline: 1.1599x; 1.1599x over previous
//
#include <hip/hip_runtime.h>
#include <math.h>

#define CCH   256
#define NPIX  4096
#define BATCH 4

typedef __attribute__((ext_vector_type(8))) short    s16x8;
typedef __attribute__((ext_vector_type(4))) short    s16x4;
typedef __attribute__((ext_vector_type(8))) _Float16 f16x8;
typedef __attribute__((ext_vector_type(4))) float    f32x4;

__device__ __forceinline__ unsigned short f2bf(float f) {
    unsigned int u = __float_as_uint(f);
    u += 0x7fff + ((u >> 16) & 1);          // RNE; values are finite
    return (unsigned short)(u >> 16);
}
__device__ __forceinline__ float bf2f(unsigned short h) {
    return __uint_as_float(((unsigned int)h) << 16);
}
__device__ __forceinline__ unsigned short f2h(float f) {
    _Float16 h = (_Float16)f;               // v_cvt_f16_f32, RNE
    return *(unsigned short*)&h;
}
__device__ __forceinline__ float h2f(unsigned short u) {
    _Float16 h = *(_Float16*)&u;
    return (float)h;
}

// q/k frag (16x16x32 A/B layout), element for (pixel n, dim d):
//   tile = n>>4, lane = (d>>3)*16 + (n&15), elem = d&7
__device__ __forceinline__ size_t qk_addr(int b, int n, int d) {
    return ((((size_t)b * 256 + (n >> 4)) * 64 + ((d >> 3) << 4) + (n & 15)) << 3) + (d & 7);
}
// v frag: standard A-layout for PV; k = j (32-step), m = c (16-tile):
__device__ __forceinline__ size_t v_addr(int b, int j, int c) {
    return ((((((size_t)b * 64 + (j >> 6)) * 16 + (c >> 4)) * 2 + ((j >> 5) & 1)) * 64
            + (((j >> 3) & 3) << 4) + (c & 15)) << 3) + (j & 7);
}

// ---------------- W -> A-frag fp16 (hi/lo for q,k; hi for v), once ----------------
__global__ __launch_bounds__(64) void wcast_kernel(
    const float* __restrict__ Wq, const float* __restrict__ bq,
    const float* __restrict__ Wk, const float* __restrict__ bk,
    const float* __restrict__ Wv, const float* __restrict__ bv,
    unsigned short* __restrict__ wfh, unsigned short* __restrict__ wfl,
    float* __restrict__ bias_ws)
{
    const int rt = blockIdx.x;
    const int lane = threadIdx.x, l15 = lane & 15, quad = lane >> 4;
    const float *Ws, *bs; int roff; float scale = 1.0f;
    if (rt < 2)      { Ws = Wq; bs = bq; roff = rt * 16;      scale = 1.44269504f; }
    else if (rt < 4) { Ws = Wk; bs = bk; roff = (rt - 2) * 16; }
    else             { Ws = Wv; bs = bv; roff = (rt - 4) * 16; }

    const float* wrow = Ws + (size_t)(roff + l15) * CCH + quad * 8;
    for (int kb = 0; kb < 8; ++kb) {
        s16x8 h, l;
        #pragma unroll
        for (int d = 0; d < 8; ++d) {
            float wv = wrow[kb * 32 + d] * scale;
            unsigned short hh = f2h(wv);
            h[d] = (short)hh;
            l[d] = (short)f2h(wv - h2f(hh));
        }
        *(s16x8*)&wfh[(((size_t)rt * 8 + kb) * 64 + lane) * 8] = h;
        if (rt < 4) *(s16x8*)&wfl[(((size_t)rt * 8 + kb) * 64 + lane) * 8] = l;
    }
    if (lane < 16) bias_ws[rt * 16 + lane] = bs[roff + lane] * scale;
}

// ---------------- fused cast+projection (LDS-staged x, fp16 internal; R12-verified) ----------------
__global__ __launch_bounds__(256, 4) void proj_kernel(
    const float* __restrict__ x,
    const unsigned short* __restrict__ wfh, const unsigned short* __restrict__ wfl,
    const float* __restrict__ bias_ws,
    unsigned short* __restrict__ q_hi, unsigned short* __restrict__ k_hi,
    unsigned short* __restrict__ v_frag)
{
    __shared__ float xs[16][260];   // [col 0..15][row 0..255], +4 pad vs 256

    const int t = threadIdx.x;
    const int rh = t >> 6, lane = t & 63, l15 = lane & 15, quad = lane >> 4;
    const int b = blockIdx.y;
    const int nt = blockIdx.x;

    // ---- cooperative stage: x[b][r][nt*16 + c] -> xs[c][r] ----
    {
        const float* xrow = x + (size_t)b * CCH * NPIX + nt * 16;
        #pragma unroll
        for (int i = 0; i < 4; ++i) {
            const int r  = i * 64 + (t >> 2);
            const int c4 = (t & 3) * 4;
            const float4 v = *(const float4*)&xrow[(size_t)r * NPIX + c4];
            xs[c4 + 0][r] = v.x;
            xs[c4 + 1][r] = v.y;
            xs[c4 + 2][r] = v.z;
            xs[c4 + 3][r] = v.w;
        }
    }
    __syncthreads();

    f32x4 aq0 = {0.f, 0.f, 0.f, 0.f};
    f32x4 aq1 = {0.f, 0.f, 0.f, 0.f};
    f32x4 av[4];
    #pragma unroll
    for (int i = 0; i < 4; ++i) av[i] = (f32x4){0.f, 0.f, 0.f, 0.f};

    #pragma unroll 2
    for (int kb = 0; kb < 8; ++kb) {
        const float4 xv0 = *(const float4*)&xs[l15][kb * 32 + quad * 8];
        const float4 xv1 = *(const float4*)&xs[l15][kb * 32 + quad * 8 + 4];
        const float xa[8] = { xv0.x, xv0.y, xv0.z, xv0.w,
                              xv1.x, xv1.y, xv1.z, xv1.w };
        f16x8 xh, xl;
        #pragma unroll
        for (int d = 0; d < 8; ++d) {
            const float xv = xa[d];
            _Float16 hh = (_Float16)xv;
            xh[d] = hh;
            xl[d] = (_Float16)(xv - (float)hh);
        }
        {
            const f16x8 ah = *(const f16x8*)&wfh[(((size_t)rh * 8 + kb) * 64 + lane) * 8];
            const f16x8 al = *(const f16x8*)&wfl[(((size_t)rh * 8 + kb) * 64 + lane) * 8];
            aq0 = __builtin_amdgcn_mfma_f32_16x16x32_f16(ah, xh, aq0, 0, 0, 0);
            aq1 = __builtin_amdgcn_mfma_f32_16x16x32_f16(ah, xl, aq1, 0, 0, 0);
            aq1 = __builtin_amdgcn_mfma_f32_16x16x32_f16(al, xh, aq1, 0, 0, 0);
        }
        #pragma unroll
        for (int i = 0; i < 4; ++i) {
            const int rt = 4 + rh * 4 + i;
            const f16x8 ah = *(const f16x8*)&wfh[(((size_t)rt * 8 + kb) * 64 + lane) * 8];
            av[i] = __builtin_amdgcn_mfma_f32_16x16x32_f16(ah, xh, av[i], 0, 0, 0);
        }
    }

    const int n = nt * 16 + l15;
    {
        s16x4 h4;
        #pragma unroll
        for (int rr = 0; rr < 4; ++rr) {
            const int rloc = quad * 4 + rr;
            const float val = aq0[rr] + aq1[rr] + bias_ws[rh * 16 + rloc];
            h4[rr] = (short)f2h(val);
        }
        if (rh < 2) {
            const size_t a = qk_addr(b, n, rh * 16 + quad * 4);
            *(s16x4*)&q_hi[a] = h4;
        } else {
            const size_t a = qk_addr(b, n, (rh - 2) * 16 + quad * 4);
            *(s16x4*)&k_hi[a] = h4;
        }
    }
    #pragma unroll
    for (int i = 0; i < 4; ++i) {
        const int vt = rh * 4 + i;
        #pragma unroll
        for (int rr = 0; rr < 4; ++rr) {
            const int rloc = quad * 4 + rr;
            const float val = av[i][rr] + bias_ws[(4 + vt) * 16 + rloc];
            v_frag[v_addr(b, n, vt * 16 + rloc)] = f2bf(val);
        }
    }
}

// ---------------- flash attention: R9-VERIFIED (56.0 us) -- byte-identical ----------------
// 512 blocks (2/CU) x 8 waves = (jh 0..1, ch 0..3).  fp16 QK (2 MFMAs/step);
// P bf16 (P = 2^s overflows fp16); 1 lgkm-barrier per j-step; V loads in
// flight across the barrier; PV under setprio(1).
// R13 lesson: lacc's ones-MFMAs ride the underutilized MFMA pipe (free);
// moving that work to VALU regressed.  R15 lesson: the 32x32 barrier-free
// rewrite is correct but occupancy-capped (64KB LDS epilogue -> 1 block/CU)
// and lands at 94us; its repaired ceiling ties this kernel within noise.
#define BARRIER_LGKM() do { \
    asm volatile("s_waitcnt lgkmcnt(0)" ::: "memory"); \
    __builtin_amdgcn_s_barrier(); \
    asm volatile("" ::: "memory"); \
} while (0)

#define QK_STEP(KF, BUFC) do { \
    f32x4 a0 = __builtin_amdgcn_mfma_f32_16x16x32_f16((KF), qf0, (f32x4){0.f,0.f,0.f,0.f}, 0, 0, 0); \
    f32x4 a1 = __builtin_amdgcn_mfma_f32_16x16x32_f16((KF), qf1, (f32x4){0.f,0.f,0.f,0.f}, 0, 0, 0); \
    unsigned int u0 = __float_as_uint(__builtin_exp2f(a0[0])) + 0x8000u; \
    unsigned int u1 = __float_as_uint(__builtin_exp2f(a0[1])) + 0x8000u; \
    unsigned int u2 = __float_as_uint(__builtin_exp2f(a0[2])) + 0x8000u; \
    unsigned int u3 = __float_as_uint(__builtin_exp2f(a0[3])) + 0x8000u; \
    uint2 pv; \
    pv.x = __builtin_amdgcn_perm(u1, u0, 0x07060302u); \
    pv.y = __builtin_amdgcn_perm(u3, u2, 0x07060302u); \
    *(uint2*)&p_lds[jh][BUFC][0 * 2 + pfrag_jj][(prow * 16 + l15) * 8 + pcol] = pv; \
    u0 = __float_as_uint(__builtin_exp2f(a1[0])) + 0x8000u; \
    u1 = __float_as_uint(__builtin_exp2f(a1[1])) + 0x8000u; \
    u2 = __float_as_uint(__builtin_exp2f(a1[2])) + 0x8000u; \
    u3 = __float_as_uint(__builtin_exp2f(a1[3])) + 0x8000u; \
    uint2 pw; \
    pw.x = __builtin_amdgcn_perm(u1, u0, 0x07060302u); \
    pw.y = __builtin_amdgcn_perm(u3, u2, 0x07060302u); \
    *(uint2*)&p_lds[jh][BUFC][1 * 2 + pfrag_jj][(prow * 16 + l15) * 8 + pcol] = pw; \
} while (0)

#define ATTN_BODY(T, BUFC, KU, KL, DO_QK) do { \
    const int jt = jh * 32 + (T); \
    const s16x8 pf0 = *(const s16x8*)&p_lds[jh][BUFC][0][lane * 8]; \
    const s16x8 pf1 = *(const s16x8*)&p_lds[jh][BUFC][1][lane * 8]; \
    const s16x8 pf2 = *(const s16x8*)&p_lds[jh][BUFC][2][lane * 8]; \
    const s16x8 pf3 = *(const s16x8*)&p_lds[jh][BUFC][3][lane * 8]; \
    const size_t vbase = (((size_t)jt * 16 + ch * 4) * 2) * 512; \
    const s16x8 v0 = *(const s16x8*)(vb + vbase); \
    const s16x8 v1 = *(const s16x8*)(vb + vbase + 512); \
    const s16x8 v2 = *(const s16x8*)(vb + vbase + 1024); \
    const s16x8 v3 = *(const s16x8*)(vb + vbase + 1536); \
    if (DO_QK) { QK_STEP(KU, (BUFC) ^ 1); } \
    { \
        const int tpp = ((T) + 2 < 32) ? (T) + 2 : 0; \
        const size_t koff = (size_t)((jh * 32 + tpp) * 4 + ch) * 512; \
        KL = *(const f16x8*)(khb + koff); \
    } \
    if (ch == 0) { \
        lacc = __builtin_amdgcn_mfma_f32_16x16x32_bf16(ones, pf0, lacc, 0, 0, 0); \
        lacc = __builtin_amdgcn_mfma_f32_16x16x32_bf16(ones, pf1, lacc, 0, 0, 0); \
    } else if (ch == 1) { \
        lacc = __builtin_amdgcn_mfma_f32_16x16x32_bf16(ones, pf2, lacc, 0, 0, 0); \
        lacc = __builtin_amdgcn_mfma_f32_16x16x32_bf16(ones, pf3, lacc, 0, 0, 0); \
    } \
    BARRIER_LGKM(); \
    const s16x8 v4 = *(const s16x8*)(vb + vbase + 2048); \
    const s16x8 v5 = *(const s16x8*)(vb + vbase + 2560); \
    const s16x8 v6 = *(const s16x8*)(vb + vbase + 3072); \
    const s16x8 v7 = *(const s16x8*)(vb + vbase + 3584); \
    __builtin_amdgcn_s_setprio(1); \
    acc[0] = __builtin_amdgcn_mfma_f32_16x16x32_bf16(v0, pf0, acc[0], 0, 0, 0); \
    acc[0] = __builtin_amdgcn_mfma_f32_16x16x32_bf16(v1, pf1, acc[0], 0, 0, 0); \
    acc[1] = __builtin_amdgcn_mfma_f32_16x16x32_bf16(v0, pf2, acc[1], 0, 0, 0); \
    acc[1] = __builtin_amdgcn_mfma_f32_16x16x32_bf16(v1, pf3, acc[1], 0, 0, 0); \
    acc[2] = __builtin_amdgcn_mfma_f32_16x16x32_bf16(v2, pf0, acc[2], 0, 0, 0); \
    acc[2] = __builtin_amdgcn_mfma_f32_16x16x32_bf16(v3, pf1, acc[2], 0, 0, 0); \
    acc[3] = __builtin_amdgcn_mfma_f32_16x16x32_bf16(v2, pf2, acc[3], 0, 0, 0); \
    acc[3] = __builtin_amdgcn_mfma_f32_16x16x32_bf16(v3, pf3, acc[3], 0, 0, 0); \
    acc[4] = __builtin_amdgcn_mfma_f32_16x16x32_bf16(v4, pf0, acc[4], 0, 0, 0); \
    acc[4] = __builtin_amdgcn_mfma_f32_16x16x32_bf16(v5, pf1, acc[4], 0, 0, 0); \
    acc[5] = __builtin_amdgcn_mfma_f32_16x16x32_bf16(v4, pf2, acc[5], 0, 0, 0); \
    acc[5] = __builtin_amdgcn_mfma_f32_16x16x32_bf16(v5, pf3, acc[5], 0, 0, 0); \
    acc[6] = __builtin_amdgcn_mfma_f32_16x16x32_bf16(v6, pf0, acc[6], 0, 0, 0); \
    acc[6] = __builtin_amdgcn_mfma_f32_16x16x32_bf16(v7, pf1, acc[6], 0, 0, 0); \
    acc[7] = __builtin_amdgcn_mfma_f32_16x16x32_bf16(v6, pf2, acc[7], 0, 0, 0); \
    acc[7] = __builtin_amdgcn_mfma_f32_16x16x32_bf16(v7, pf3, acc[7], 0, 0, 0); \
    __builtin_amdgcn_s_setprio(0); \
} while (0)

__global__ __launch_bounds__(512, 4) void attn_kernel(
    const unsigned short* __restrict__ q_hi,
    const unsigned short* __restrict__ k_hi,
    const unsigned short* __restrict__ v_frag,
    const float* __restrict__ x, float* __restrict__ out)
{
    __shared__ unsigned short p_lds[2][2][4][512];   // [jh][dbuf][frag][lane*8] = 16 KB
    __shared__ f32x4 comb[2][4][4][64];              // [jh_src][ch][ct][lane] = 32 KB
    __shared__ float lds_l[2][2][16];

    const int t = threadIdx.x;
    const int w = t >> 6, lane = t & 63, l15 = lane & 15, quad = lane >> 4;
    const int jh = w >> 2, ch = w & 3;

    const int f = blockIdx.x;                 // 0..511; XCD-pair per batch
    const int xcd = f & 7;
    const int b = xcd >> 1;
    const int ib = ((xcd & 1) << 6) + (f >> 3);   // i-block 0..127 (32 pixels)

    f16x8 qf0, qf1;
    {
        const size_t qo0 = ((size_t)b * 256 + ib * 2 + 0) * 512 + (size_t)lane * 8;
        const size_t qo1 = ((size_t)b * 256 + ib * 2 + 1) * 512 + (size_t)lane * 8;
        qf0 = *(const f16x8*)(q_hi + qo0);
        qf1 = *(const f16x8*)(q_hi + qo1);
    }

    const s16x8 ones = { (short)0x3F80, (short)0x3F80, (short)0x3F80, (short)0x3F80,
                         (short)0x3F80, (short)0x3F80, (short)0x3F80, (short)0x3F80 };

    f32x4 acc[8];                             // [ct*2+it], constant indices only
    #pragma unroll
    for (int i = 0; i < 8; ++i) acc[i] = (f32x4){0.f, 0.f, 0.f, 0.f};
    f32x4 lacc = {0.f, 0.f, 0.f, 0.f};

    const unsigned short* khb = k_hi + (size_t)b * 131072 + (size_t)lane * 8;
    const unsigned short* vb  = v_frag + (size_t)b * 1048576 + (size_t)lane * 8;

    const int prow = ((ch & 1) << 1) + (quad >> 1);
    const int pcol = ((quad & 1) << 2);
    const int pfrag_jj = ch >> 1;

    // ---- prologue: K(0) -> QK(0) -> P(0) in buf0; prefetch K(1) ----
    f16x8 ka, kb;
    {
        const size_t k0 = (size_t)((jh * 32 + 0) * 4 + ch) * 512;
        ka = *(const f16x8*)(khb + k0);
    }
    QK_STEP(ka, 0);
    {
        const size_t k1 = (size_t)((jh * 32 + 1) * 4 + ch) * 512;
        ka = *(const f16x8*)(khb + k1);
    }
    BARRIER_LGKM();

    #pragma unroll 1
    for (int t2 = 0; t2 < 16; ++t2) {
        ATTN_BODY(2 * t2,     0, ka, kb, 1);
        ATTN_BODY(2 * t2 + 1, 1, kb, ka, (t2 < 15));
    }

    // ---- epilogue (constant indices inside wave-uniform branches) ----
    if (ch < 2 && lane < 16) lds_l[jh][ch][lane] = lacc[0];
    if (jh == 0) {          // own it0; publish it1
        #pragma unroll
        for (int ct = 0; ct < 4; ++ct)
            comb[0][ch][ct][lane] = acc[ct * 2 + 1];
    } else {                // own it1; publish it0
        #pragma unroll
        for (int ct = 0; ct < 4; ++ct)
            comb[1][ch][ct][lane] = acc[ct * 2 + 0];
    }
    __syncthreads();
    const float linv = 1.f / (lds_l[0][jh][l15] + lds_l[1][jh][l15]);
    const int ibase = (ib * 2 + jh) * 16 + l15;
    #pragma unroll
    for (int ct = 0; ct < 4; ++ct) {
        f32x4 a;
        if (jh == 0) a = acc[ct * 2 + 0];
        else         a = acc[ct * 2 + 1];
        a += comb[1 - jh][ch][ct][lane];
        #pragma unroll
        for (int rr = 0; rr < 4; ++rr) {
            const int c = ch * 64 + ct * 16 + quad * 4 + rr;
            const size_t idx = ((size_t)b * CCH + c) * NPIX + ibase;
            out[idx] = a[rr] * linv + x[idx];
        }
    }
}

extern "C" void kernel_launch(void* const* d_in, const int* in_sizes, int n_in,
                              void* d_out, int out_size, void* d_ws, size_t ws_size,
                              hipStream_t stream) {
    const float* x  = (const float*)d_in[0];
    const float* Wq = (const float*)d_in[1];
    const float* bq = (const float*)d_in[2];
    const float* Wk = (const float*)d_in[3];
    const float* bk = (const float*)d_in[4];
    const float* Wv = (const float*)d_in[5];
    const float* bv = (const float*)d_in[6];
    float* out = (float*)d_out;

    unsigned short* ws = (unsigned short*)d_ws;
    unsigned short* q_hi   = ws;                 //   524,288 (fp16)
    unsigned short* k_hi   = ws + 1048576;       //   524,288 (fp16)
    unsigned short* v_frag = ws + 2097152;       // 4,194,304 (bf16)
    unsigned short* wfh    = ws + 6291456;       //    81,920 (fp16)
    unsigned short* wfl    = ws + 6373376;       //    16,384 (fp16)
    float*          bias_ws = (float*)(ws + 6389760);  // 320 floats

    wcast_kernel<<<20, 64, 0, stream>>>(Wq, bq, Wk, bk, Wv, bv, wfh, wfl, bias_ws);
    proj_kernel<<<dim3(256, BATCH), 256, 0, stream>>>(x, wfh, wfl, bias_ws,
                                                      q_hi, k_hi, v_frag);
    attn_kernel<<<512, 512, 0, stream>>>(q_hi, k_hi, v_frag, x, out);
}